// Round 4
// baseline (78.634 us; speedup 1.0000x reference)
//
#include <hip/hip_runtime.h>
#include <hip/hip_bf16.h>
#include <stdint.h>

constexpr int NUM_NODES = 120000;
constexpr int Tn = 10;
constexpr int Bb = 64, Rr = 4, Nn = 64, Cc = 64, Ii = 64;
constexpr int G  = 8;           // sequences per block
constexpr int M  = 80;          // columns per block (G*Tn)
constexpr int NT = 5;           // 16-wide col tiles
constexpr int RSTR  = 147456;   // per-relation Wf stride (bf16 elems)
constexpr int OFF0  = 0;        // L0 w1   [tap2][ct4][ks4][lane64][8]
constexpr int OFF1  = 16384;    // L0 down [ct4][ks4][lane64][8]
constexpr int OFF2  = 24576;    // L0 w2   [tap2][ct4][ks2][lane64][8]
constexpr int OFFL0 = 32768;    // levels  14 x [tap2][ct4][ks2][lane64][8]

typedef __attribute__((ext_vector_type(8))) short bf16x8;
typedef __attribute__((ext_vector_type(4))) float f32x4;
typedef __attribute__((ext_vector_type(4))) short s16x4;

__device__ __forceinline__ short f2bf(float f) {
  __hip_bfloat16 h = __float2bfloat16(f);
  return *reinterpret_cast<short*>(&h);
}

// ---------------------------------------------------------------------------
// Bake weights into per-lane MFMA A-fragments (bf16).
// A-frag for 16x16x32: lane holds A[ct*16 + (lane&15)][ks*32 + (lane>>4)*8 + j]
// ---------------------------------------------------------------------------
extern "C" __global__ void prep_kernel(const float* __restrict__ w1_0,
                                       const float* __restrict__ w2_0,
                                       const float* __restrict__ down_w,
                                       const float* __restrict__ w1s,
                                       const float* __restrict__ w2s,
                                       short* __restrict__ Wf) {
  int i0 = blockIdx.x * blockDim.x + threadIdx.x;
  int stride = gridDim.x * blockDim.x;
  for (int e = i0; e < Rr * RSTR; e += stride) {
    int r = e / RSTR, q = e - r * RSTR;
    float v;
    if (q < 16384) {                 // L0 w1 (CIN=128, 2 taps)
      int j = q & 7, lane = (q >> 3) & 63, ks = (q >> 9) & 3, ct = (q >> 11) & 3, tap = (q >> 13) & 1;
      int cout = ct * 16 + (lane & 15), cin = ks * 32 + (lane >> 4) * 8 + j;
      v = w1_0[((r * 64 + cout) * 128 + cin) * 2 + tap];
    } else if (q < 24576) {          // L0 down (CIN=128, 1 tap)
      int q2 = q - 16384;
      int j = q2 & 7, lane = (q2 >> 3) & 63, ks = (q2 >> 9) & 3, ct = (q2 >> 11) & 3;
      int cout = ct * 16 + (lane & 15), cin = ks * 32 + (lane >> 4) * 8 + j;
      v = down_w[(r * 64 + cout) * 128 + cin];
    } else if (q < 32768) {          // L0 w2 (CIN=64, 2 taps)
      int q2 = q - 24576;
      int j = q2 & 7, lane = (q2 >> 3) & 63, ks = (q2 >> 9) & 1, ct = (q2 >> 10) & 3, tap = (q2 >> 12) & 1;
      int cout = ct * 16 + (lane & 15), cin = ks * 32 + (lane >> 4) * 8 + j;
      v = w2_0[((r * 64 + cout) * 64 + cin) * 2 + tap];
    } else {                         // levels 1..7, convs w1/w2
      int q2 = q - 32768;
      int lc = q2 >> 13;             // 0..13
      int l = lc >> 1, jw = lc & 1;  // level (l+1), conv index
      int q3 = q2 & 8191;
      int j = q3 & 7, lane = (q3 >> 3) & 63, ks = (q3 >> 9) & 1, ct = (q3 >> 10) & 3, tap = (q3 >> 12) & 1;
      int cout = ct * 16 + (lane & 15), cin = ks * 32 + (lane >> 4) * 8 + j;
      const float* src = jw ? w2s : w1s;
      v = src[(((r * 7 + l) * 64 + cout) * 64 + cin) * 2 + tap];
    }
    Wf[e] = f2bf(v);
  }
}

// ---------------------------------------------------------------------------
// One causal-conv GEMM pass. X in LDS as [m][cin] bf16, XOR-swizzled.
// ---------------------------------------------------------------------------
template <int KSN, int NTAP, int TAPOFF, int ROWB>
__device__ __forceinline__ void conv_pass(const char* __restrict__ src,
                                          const short* __restrict__ wf,
                                          const float* __restrict__ bias, int d,
                                          int lane, int ct, const int (&marr)[NT],
                                          const int (&tarr)[NT], f32x4 (&acc)[NT]) {
  const int chunk16 = (lane >> 4) * 16;
  float bv[4];
#pragma unroll
  for (int g = 0; g < 4; ++g) bv[g] = bias[ct * 16 + (lane >> 4) * 4 + g];
#pragma unroll
  for (int tile = 0; tile < NT; ++tile) acc[tile] = (f32x4){bv[0], bv[1], bv[2], bv[3]};
  bf16x8 af[NTAP][KSN];
#pragma unroll
  for (int tp = 0; tp < NTAP; ++tp)
#pragma unroll
    for (int ks = 0; ks < KSN; ++ks)
      af[tp][ks] = *(const bf16x8*)(wf + ((((tp + TAPOFF) * 4 + ct) * KSN + ks) * 64 + lane) * 8);
#pragma unroll
  for (int tile = 0; tile < NT; ++tile) {
    int m = marr[tile];
    int rb = m * ROWB, sw = (m & 7) << 4;
#pragma unroll
    for (int ks = 0; ks < KSN; ++ks) {
      bf16x8 bf = *(const bf16x8*)(src + rb + ((ks * 64 + chunk16) ^ sw));
      acc[tile] = __builtin_amdgcn_mfma_f32_16x16x32_bf16(af[NTAP - 1][ks], bf, acc[tile], 0, 0, 0);
    }
    if (NTAP == 2) {
      int m0 = (tarr[tile] >= d) ? (m - d) : M;  // row M = persistent zero row
      int rb0 = m0 * ROWB, sw0 = (m0 & 7) << 4;
#pragma unroll
      for (int ks = 0; ks < KSN; ++ks) {
        bf16x8 bf = *(const bf16x8*)(src + rb0 + ((ks * 64 + chunk16) ^ sw0));
        acc[tile] = __builtin_amdgcn_mfma_f32_16x16x32_bf16(af[0][ks], bf, acc[tile], 0, 0, 0);
      }
    }
  }
}

__device__ __forceinline__ void store_tiles(char* __restrict__ dst, int lane, int ct,
                                            const int (&marr)[NT], const f32x4 (&v)[NT]) {
  const int co = ct * 32 + (lane >> 4) * 8;
#pragma unroll
  for (int tile = 0; tile < NT; ++tile) {
    int m = marr[tile];
    s16x4 p;
#pragma unroll
    for (int g = 0; g < 4; ++g) p[g] = f2bf(v[tile][g]);
    *(s16x4*)(dst + m * 128 + (co ^ ((m & 7) << 4))) = p;
  }
}

// ---------------------------------------------------------------------------
// Main. Block = (r, b, chunk-of-8-VALID-neighbors). Ballot-compaction picks
// the chunk's neighbors; blocks past the valid count write zero partials and
// exit before any gather/conv work.
// ---------------------------------------------------------------------------
extern "C" __global__ void __launch_bounds__(256, 3)
tcn_mfma(const float* __restrict__ emb, const int* __restrict__ align_,
         const int* __restrict__ nidx, const int* __restrict__ nmask,
         const float* __restrict__ b1_0, const float* __restrict__ b2_0,
         const float* __restrict__ down_b, const float* __restrict__ b1s,
         const float* __restrict__ b2s, const short* __restrict__ Wf,
         float* __restrict__ P) {
  __shared__ char smem[41472];   // XE [81][256B] | H [81][128B] | Y [81][128B]
  __shared__ int rowid[M];
  __shared__ float mkv[G];
  __shared__ int mapg[G];
  __shared__ int totv;
  char* XE = smem;
  char* Hb = smem + 20736;
  char* Yb = smem + 31104;

  const int tid = threadIdx.x;
  const int lane = tid & 63, ct = tid >> 6;
  const int blk = blockIdx.x;
  const int r = blk >> 9;
  const int blkr = blk & 511;
  const int b = blkr >> 3, chunk = blkr & 7;

  // ---- ballot compaction of this (b,r)'s valid neighbors ----
  if (tid < 64) {
    int n = tid;
    int msk = nmask[(b * Rr + r) * Nn + n];
    unsigned long long bal = __ballot(msk != 0);
    if (tid < G) mapg[tid] = -1;
    if (tid == 0) totv = (int)__popcll(bal);
    int rank = (int)__popcll(bal & ((1ull << n) - 1ull));
    if (msk != 0 && rank >= chunk * G && rank < chunk * G + G)
      mapg[rank - chunk * G] = n;
  }
  __syncthreads();
  if (chunk * G >= totv) {           // inactive block: zero partial, exit
    if (tid < 64) P[((r * Bb + b) * 8 + chunk) * 64 + tid] = 0.f;
    return;
  }

  if (tid < M) {
    int g = tid / 10, t = tid - g * 10;
    int n2 = mapg[g];
    int s = -1;
    if (n2 >= 0) {
      int ent = nidx[(b * Rr + r) * Nn + n2];
      s = align_[ent * Tn + t];
    }
    rowid[tid] = (n2 >= 0 && s >= 0) ? s : -1;
    if (t == 0) mkv[g] = (n2 >= 0) ? 1.0f : 0.0f;
  }
  if (tid >= 128 && tid < 160) *(uint64_t*)(XE + 80 * 256 + (tid - 128) * 8) = 0;
  if (tid >= 160 && tid < 176) *(uint64_t*)(Hb + 80 * 128 + (tid - 160) * 8) = 0;
  if (tid >= 176 && tid < 192) *(uint64_t*)(Yb + 80 * 128 + (tid - 176) * 8) = 0;
  __syncthreads();

  // gather: 80 rows x 128 d, f32 -> bf16, swizzled LDS write
#pragma unroll
  for (int it = 0; it < 10; ++it) {
    int idx = tid + it * 256;
    int m = idx >> 5, d4 = idx & 31;
    int row = rowid[m];
    int t = m % 10;
    s16x4 p = {0, 0, 0, 0};
    if (row >= 0) {
      const float4 v = *(const float4*)(emb + ((size_t)t * NUM_NODES + row) * 128 + d4 * 4);
      p[0] = f2bf(v.x); p[1] = f2bf(v.y); p[2] = f2bf(v.z); p[3] = f2bf(v.w);
    }
    *(s16x4*)(XE + m * 256 + ((d4 * 8) ^ ((m & 7) << 4))) = p;
  }
  __syncthreads();

  int marr[NT], tarr[NT];
#pragma unroll
  for (int tile = 0; tile < NT; ++tile) {
    marr[tile] = tile * 16 + (lane & 15);
    tarr[tile] = marr[tile] % 10;
  }

  const short* wr = Wf + r * RSTR;
  f32x4 acc[NT], acc2[NT], hreg[NT];

  // ---- level 0 ----
  conv_pass<4, 2, 0, 256>(XE, wr + OFF0, b1_0 + r * 64, 1, lane, ct, marr, tarr, acc);
#pragma unroll
  for (int tl = 0; tl < NT; ++tl)
#pragma unroll
    for (int g2 = 0; g2 < 4; ++g2) acc[tl][g2] = fmaxf(acc[tl][g2], 0.f);
  store_tiles(Yb, lane, ct, marr, acc);
  __syncthreads();
  conv_pass<2, 2, 0, 128>(Yb, wr + OFF2, b2_0 + r * 64, 1, lane, ct, marr, tarr, acc2);
  conv_pass<4, 1, 0, 256>(XE, wr + OFF1, down_b + r * 64, 0, lane, ct, marr, tarr, acc);
#pragma unroll
  for (int tl = 0; tl < NT; ++tl)
#pragma unroll
    for (int g2 = 0; g2 < 4; ++g2)
      hreg[tl][g2] = fmaxf(fmaxf(acc2[tl][g2], 0.f) + acc[tl][g2], 0.f);
  store_tiles(Hb, lane, ct, marr, hreg);
  __syncthreads();

  // ---- levels 1..7 ----
#define LEVEL(l, dd, NTAPv, TOFFv)                                                   \
  {                                                                                  \
    conv_pass<2, NTAPv, TOFFv, 128>(Hb, wr + OFFL0 + ((l - 1) * 2 + 0) * 8192,       \
                                    b1s + (r * 7 + (l - 1)) * 64, dd, lane, ct,      \
                                    marr, tarr, acc);                                \
    _Pragma("unroll") for (int tl = 0; tl < NT; ++tl)                                \
        _Pragma("unroll") for (int g2 = 0; g2 < 4; ++g2)                             \
            acc[tl][g2] = fmaxf(acc[tl][g2], 0.f);                                   \
    store_tiles(Yb, lane, ct, marr, acc);                                            \
    __syncthreads();                                                                 \
    conv_pass<2, NTAPv, TOFFv, 128>(Yb, wr + OFFL0 + ((l - 1) * 2 + 1) * 8192,       \
                                    b2s + (r * 7 + (l - 1)) * 64, dd, lane, ct,      \
                                    marr, tarr, acc);                                \
    _Pragma("unroll") for (int tl = 0; tl < NT; ++tl)                                \
        _Pragma("unroll") for (int g2 = 0; g2 < 4; ++g2)                             \
            hreg[tl][g2] = fmaxf(fmaxf(acc[tl][g2], 0.f) + hreg[tl][g2], 0.f);       \
    store_tiles(Hb, lane, ct, marr, hreg);                                           \
    __syncthreads();                                                                 \
  }
  LEVEL(1, 2, 2, 0)
  LEVEL(2, 4, 2, 0)
  LEVEL(3, 8, 2, 0)
  LEVEL(4, 16, 1, 1)
  LEVEL(5, 32, 1, 1)
  LEVEL(6, 64, 1, 1)
  LEVEL(7, 128, 1, 1)
#undef LEVEL

  // ---- epilogue: masked last-step (t==9), reduce over 8 sequences ----
  float s0 = 0, s1 = 0, s2 = 0, s3 = 0;
#pragma unroll
  for (int tl = 0; tl < NT; ++tl) {
    float mk = (tarr[tl] == 9) ? mkv[marr[tl] / 10] : 0.f;
    s0 += hreg[tl][0] * mk;
    s1 += hreg[tl][1] * mk;
    s2 += hreg[tl][2] * mk;
    s3 += hreg[tl][3] * mk;
  }
#pragma unroll
  for (int mk2 = 1; mk2 <= 8; mk2 <<= 1) {
    s0 += __shfl_xor(s0, mk2);
    s1 += __shfl_xor(s1, mk2);
    s2 += __shfl_xor(s2, mk2);
    s3 += __shfl_xor(s3, mk2);
  }
  if ((lane & 15) == 0) {
    int base = ((r * Bb + b) * 8 + chunk) * 64 + ct * 16 + (lane >> 4) * 4;
    P[base + 0] = s0;
    P[base + 1] = s1;
    P[base + 2] = s2;
    P[base + 3] = s3;
  }
}

// ---------------------------------------------------------------------------
// out[b][i] = sum_r sum_c (sum_p P[r][b][p][c]) * rel_w[r][c][i]
// ---------------------------------------------------------------------------
extern "C" __global__ void reduce_kernel(const float* __restrict__ P,
                                         const float* __restrict__ rel_w,
                                         float* __restrict__ out) {
  __shared__ float Sl[Rr * Cc];
  int b = blockIdx.x, i = threadIdx.x;
  for (int idx = i; idx < Rr * Cc; idx += 64) {
    int rr = idx >> 6, cc = idx & 63;
    float s = 0.f;
    for (int p = 0; p < 8; ++p) s += P[((rr * Bb + b) * 8 + p) * 64 + cc];
    Sl[idx] = s;
  }
  __syncthreads();
  float acc = 0.f;
  for (int r = 0; r < Rr; ++r)
#pragma unroll
    for (int cc = 0; cc < 64; ++cc)
      acc += Sl[r * Cc + cc] * rel_w[(r * Cc + cc) * Ii + i];
  out[b * Ii + i] = acc;
}

// ---------------------------------------------------------------------------
extern "C" void kernel_launch(void* const* d_in, const int* in_sizes, int n_in,
                              void* d_out, int out_size, void* d_ws, size_t ws_size,
                              hipStream_t stream) {
  const float* emb    = (const float*)d_in[0];
  const float* w1_0   = (const float*)d_in[1];
  const float* b1_0   = (const float*)d_in[2];
  const float* w2_0   = (const float*)d_in[3];
  const float* b2_0   = (const float*)d_in[4];
  const float* down_w = (const float*)d_in[5];
  const float* down_b = (const float*)d_in[6];
  const float* w1s    = (const float*)d_in[7];
  const float* b1s    = (const float*)d_in[8];
  const float* w2s    = (const float*)d_in[9];
  const float* b2s    = (const float*)d_in[10];
  const float* rel_w  = (const float*)d_in[11];
  const int* align_   = (const int*)d_in[12];
  const int* nidx     = (const int*)d_in[13];
  const int* nmask    = (const int*)d_in[14];

  float* P  = (float*)d_ws;                       // 4*64*8*64 f32 = 512 KB
  short* Wf = (short*)((char*)d_ws + 524288);     // 589824 bf16 = 1.15 MB

  prep_kernel<<<768, 256, 0, stream>>>(w1_0, w2_0, down_w, w1s, w2s, Wf);
  tcn_mfma<<<2048, 256, 0, stream>>>(emb, align_, nidx, nmask, b1_0, b2_0, down_b,
                                     b1s, b2s, Wf, P);
  reduce_kernel<<<Bb, Cc, 0, stream>>>(P, rel_w, (float*)d_out);
}

// Round 5
// 75.984 us; speedup vs baseline: 1.0349x; 1.0349x over previous
//
#include <hip/hip_runtime.h>
#include <hip/hip_bf16.h>
#include <stdint.h>

constexpr int NUM_NODES = 120000;
constexpr int Tn = 10;
constexpr int Bb = 64, Rr = 4, Nn = 64, Cc = 64, Ii = 64;
constexpr int G  = 8;           // sequences per block
constexpr int M  = 80;          // columns per block (G*Tn)
constexpr int NT = 5;           // 16-wide col tiles
constexpr int RSTR  = 147456;   // per-relation Wf stride (bf16 elems)
constexpr int OFF0  = 0;        // L0 w1   [tap2][ct4][ks4][lane64][8]
constexpr int OFF1  = 16384;    // L0 down [ct4][ks4][lane64][8]
constexpr int OFF2  = 24576;    // L0 w2   [tap2][ct4][ks2][lane64][8]
constexpr int OFFL0 = 32768;    // levels  14 x [tap2][ct4][ks2][lane64][8]

typedef __attribute__((ext_vector_type(8))) short bf16x8;
typedef __attribute__((ext_vector_type(4))) float f32x4;
typedef __attribute__((ext_vector_type(4))) short s16x4;

__device__ __forceinline__ short f2bf(float f) {
  __hip_bfloat16 h = __float2bfloat16(f);
  return *reinterpret_cast<short*>(&h);
}

// ---------------------------------------------------------------------------
// Bake weights into per-lane MFMA A-fragments (bf16).
// ---------------------------------------------------------------------------
extern "C" __global__ void prep_kernel(const float* __restrict__ w1_0,
                                       const float* __restrict__ w2_0,
                                       const float* __restrict__ down_w,
                                       const float* __restrict__ w1s,
                                       const float* __restrict__ w2s,
                                       short* __restrict__ Wf) {
  int i0 = blockIdx.x * blockDim.x + threadIdx.x;
  int stride = gridDim.x * blockDim.x;
  for (int e = i0; e < Rr * RSTR; e += stride) {
    int r = e / RSTR, q = e - r * RSTR;
    float v;
    if (q < 16384) {                 // L0 w1 (CIN=128, 2 taps)
      int j = q & 7, lane = (q >> 3) & 63, ks = (q >> 9) & 3, ct = (q >> 11) & 3, tap = (q >> 13) & 1;
      int cout = ct * 16 + (lane & 15), cin = ks * 32 + (lane >> 4) * 8 + j;
      v = w1_0[((r * 64 + cout) * 128 + cin) * 2 + tap];
    } else if (q < 24576) {          // L0 down (CIN=128, 1 tap)
      int q2 = q - 16384;
      int j = q2 & 7, lane = (q2 >> 3) & 63, ks = (q2 >> 9) & 3, ct = (q2 >> 11) & 3;
      int cout = ct * 16 + (lane & 15), cin = ks * 32 + (lane >> 4) * 8 + j;
      v = down_w[(r * 64 + cout) * 128 + cin];
    } else if (q < 32768) {          // L0 w2 (CIN=64, 2 taps)
      int q2 = q - 24576;
      int j = q2 & 7, lane = (q2 >> 3) & 63, ks = (q2 >> 9) & 1, ct = (q2 >> 10) & 3, tap = (q2 >> 12) & 1;
      int cout = ct * 16 + (lane & 15), cin = ks * 32 + (lane >> 4) * 8 + j;
      v = w2_0[((r * 64 + cout) * 64 + cin) * 2 + tap];
    } else {                         // levels 1..7, convs w1/w2
      int q2 = q - 32768;
      int lc = q2 >> 13;             // 0..13
      int l = lc >> 1, jw = lc & 1;
      int q3 = q2 & 8191;
      int j = q3 & 7, lane = (q3 >> 3) & 63, ks = (q3 >> 9) & 1, ct = (q3 >> 10) & 3, tap = (q3 >> 12) & 1;
      int cout = ct * 16 + (lane & 15), cin = ks * 32 + (lane >> 4) * 8 + j;
      const float* src = jw ? w2s : w1s;
      v = src[(((r * 7 + l) * 64 + cout) * 64 + cin) * 2 + tap];
    }
    Wf[e] = f2bf(v);
  }
}

// ---------------------------------------------------------------------------
// Compile-time conv pass (level 0 only).
// ---------------------------------------------------------------------------
template <int KSN, int NTAP, int ROWB>
__device__ __forceinline__ void conv_pass(const char* __restrict__ src,
                                          const short* __restrict__ wf,
                                          const float* __restrict__ bias, int d,
                                          int lane, int ct, const int (&marr)[NT],
                                          const int (&tarr)[NT], f32x4 (&acc)[NT]) {
  const int chunk16 = (lane >> 4) * 16;
  float bv[4];
#pragma unroll
  for (int g = 0; g < 4; ++g) bv[g] = bias[ct * 16 + (lane >> 4) * 4 + g];
#pragma unroll
  for (int tile = 0; tile < NT; ++tile) acc[tile] = (f32x4){bv[0], bv[1], bv[2], bv[3]};
  bf16x8 af[NTAP][KSN];
#pragma unroll
  for (int tp = 0; tp < NTAP; ++tp)
#pragma unroll
    for (int ks = 0; ks < KSN; ++ks)
      af[tp][ks] = *(const bf16x8*)(wf + (((tp * 4 + ct) * KSN + ks) * 64 + lane) * 8);
#pragma unroll
  for (int tile = 0; tile < NT; ++tile) {
    int m = marr[tile];
    int rb = m * ROWB, sw = (m & 7) << 4;
#pragma unroll
    for (int ks = 0; ks < KSN; ++ks) {
      bf16x8 bf = *(const bf16x8*)(src + rb + ((ks * 64 + chunk16) ^ sw));
      acc[tile] = __builtin_amdgcn_mfma_f32_16x16x32_bf16(af[NTAP - 1][ks], bf, acc[tile], 0, 0, 0);
    }
    if (NTAP == 2) {
      int m0 = (tarr[tile] >= d) ? (m - d) : M;  // row M = persistent zero row
      int rb0 = m0 * ROWB, sw0 = (m0 & 7) << 4;
#pragma unroll
      for (int ks = 0; ks < KSN; ++ks) {
        bf16x8 bf = *(const bf16x8*)(src + rb0 + ((ks * 64 + chunk16) ^ sw0));
        acc[tile] = __builtin_amdgcn_mfma_f32_16x16x32_bf16(af[0][ks], bf, acc[tile], 0, 0, 0);
      }
    }
  }
}

// ---------------------------------------------------------------------------
// Runtime-tap conv pass for the rolled level loop (KSN=2, ROWB=128,
// weight layout [tap2][ct4][ks2][lane64][8]).
// ---------------------------------------------------------------------------
__device__ __forceinline__ void conv_rt(const char* __restrict__ src,
                                        const short* __restrict__ wf,
                                        const float* __restrict__ bias, int d,
                                        bool two_tap, int lane, int ct,
                                        const int (&marr)[NT], const int (&tarr)[NT],
                                        f32x4 (&acc)[NT]) {
  const int chunk16 = (lane >> 4) * 16;
  float bv[4];
#pragma unroll
  for (int g = 0; g < 4; ++g) bv[g] = bias[ct * 16 + (lane >> 4) * 4 + g];
#pragma unroll
  for (int tile = 0; tile < NT; ++tile) acc[tile] = (f32x4){bv[0], bv[1], bv[2], bv[3]};
  bf16x8 af1[2], af0[2];
#pragma unroll
  for (int ks = 0; ks < 2; ++ks)
    af1[ks] = *(const bf16x8*)(wf + (((4 + ct) * 2 + ks) * 64 + lane) * 8);
  if (two_tap) {
#pragma unroll
    for (int ks = 0; ks < 2; ++ks)
      af0[ks] = *(const bf16x8*)(wf + (((ct) * 2 + ks) * 64 + lane) * 8);
  }
#pragma unroll
  for (int tile = 0; tile < NT; ++tile) {
    int m = marr[tile];
    int rb = m * 128, sw = (m & 7) << 4;
#pragma unroll
    for (int ks = 0; ks < 2; ++ks) {
      bf16x8 bf = *(const bf16x8*)(src + rb + ((ks * 64 + chunk16) ^ sw));
      acc[tile] = __builtin_amdgcn_mfma_f32_16x16x32_bf16(af1[ks], bf, acc[tile], 0, 0, 0);
    }
    if (two_tap) {
      int m0 = (tarr[tile] >= d) ? (m - d) : M;
      int rb0 = m0 * 128, sw0 = (m0 & 7) << 4;
#pragma unroll
      for (int ks = 0; ks < 2; ++ks) {
        bf16x8 bf = *(const bf16x8*)(src + rb0 + ((ks * 64 + chunk16) ^ sw0));
        acc[tile] = __builtin_amdgcn_mfma_f32_16x16x32_bf16(af0[ks], bf, acc[tile], 0, 0, 0);
      }
    }
  }
}

__device__ __forceinline__ void store_tiles(char* __restrict__ dst, int lane, int ct,
                                            const int (&marr)[NT], const f32x4 (&v)[NT]) {
  const int co = ct * 32 + (lane >> 4) * 8;
#pragma unroll
  for (int tile = 0; tile < NT; ++tile) {
    int m = marr[tile];
    s16x4 p;
#pragma unroll
    for (int g = 0; g < 4; ++g) p[g] = f2bf(v[tile][g]);
    *(s16x4*)(dst + m * 128 + (co ^ ((m & 7) << 4))) = p;
  }
}

// ---------------------------------------------------------------------------
// Main. LDS aliasing: XE (level-0 input, 20.7 KB) is dead after level 0;
// H aliases XE. Total LDS ~31 KB -> 4-5 blocks/CU (was 3).
// ---------------------------------------------------------------------------
extern "C" __global__ void __launch_bounds__(256, 4)
tcn_mfma(const float* __restrict__ emb, const int* __restrict__ align_,
         const int* __restrict__ nidx, const int* __restrict__ nmask,
         const float* __restrict__ b1_0, const float* __restrict__ b2_0,
         const float* __restrict__ down_b, const float* __restrict__ b1s,
         const float* __restrict__ b2s, const short* __restrict__ Wf,
         float* __restrict__ P) {
  __shared__ char smem[31104];   // XE [81][256B] ; Y [81][128B] ; H aliases XE
  __shared__ int rowid[M];
  __shared__ float mkv[G];
  __shared__ int mapg[G];
  __shared__ int totv;
  char* XE = smem;
  char* Yb = smem + 20736;
  char* Hb = smem;               // alias: valid after level 0

  const int tid = threadIdx.x;
  const int lane = tid & 63, ct = tid >> 6;
  const int blk = blockIdx.x;
  const int r = blk >> 9;
  const int blkr = blk & 511;
  const int b = blkr >> 3, chunk = blkr & 7;

  // ---- ballot compaction of this (b,r)'s valid neighbors ----
  if (tid < 64) {
    int n = tid;
    int msk = nmask[(b * Rr + r) * Nn + n];
    unsigned long long bal = __ballot(msk != 0);
    if (tid < G) mapg[tid] = -1;
    if (tid == 0) totv = (int)__popcll(bal);
    int rank = (int)__popcll(bal & ((1ull << n) - 1ull));
    if (msk != 0 && rank >= chunk * G && rank < chunk * G + G)
      mapg[rank - chunk * G] = n;
  }
  __syncthreads();
  if (chunk * G >= totv) {           // inactive block: zero partial, exit
    if (tid < 64) P[((r * Bb + b) * 8 + chunk) * 64 + tid] = 0.f;
    return;
  }

  if (tid < M) {
    int g = tid / 10, t = tid - g * 10;
    int n2 = mapg[g];
    int s = -1;
    if (n2 >= 0) {
      int ent = nidx[(b * Rr + r) * Nn + n2];
      s = align_[ent * Tn + t];
    }
    rowid[tid] = (n2 >= 0 && s >= 0) ? s : -1;
    if (t == 0) mkv[g] = (n2 >= 0) ? 1.0f : 0.0f;
  }
  // zero rows (row M=80): XE row 80 (256B), Yb row 80 (128B)
  if (tid >= 128 && tid < 160) *(uint64_t*)(XE + 80 * 256 + (tid - 128) * 8) = 0;
  if (tid >= 160 && tid < 176) *(uint64_t*)(Yb + 80 * 128 + (tid - 160) * 8) = 0;
  __syncthreads();

  // gather: 80 rows x 128 d, f32 -> bf16, swizzled LDS write
#pragma unroll
  for (int it = 0; it < 10; ++it) {
    int idx = tid + it * 256;
    int m = idx >> 5, d4 = idx & 31;
    int row = rowid[m];
    int t = m % 10;
    s16x4 p = {0, 0, 0, 0};
    if (row >= 0) {
      const float4 v = *(const float4*)(emb + ((size_t)t * NUM_NODES + row) * 128 + d4 * 4);
      p[0] = f2bf(v.x); p[1] = f2bf(v.y); p[2] = f2bf(v.z); p[3] = f2bf(v.w);
    }
    *(s16x4*)(XE + m * 256 + ((d4 * 8) ^ ((m & 7) << 4))) = p;
  }
  __syncthreads();

  int marr[NT], tarr[NT];
#pragma unroll
  for (int tile = 0; tile < NT; ++tile) {
    marr[tile] = tile * 16 + (lane & 15);
    tarr[tile] = marr[tile] % 10;
  }

  const short* wr = Wf + r * RSTR;
  f32x4 acc[NT], hreg[NT];

  // ---- level 0: conv1 -> Yb; down -> hreg (regs); XE dead after this ----
  conv_pass<4, 2, 256>(XE, wr + OFF0, b1_0 + r * 64, 1, lane, ct, marr, tarr, acc);
#pragma unroll
  for (int tl = 0; tl < NT; ++tl)
#pragma unroll
    for (int g2 = 0; g2 < 4; ++g2) acc[tl][g2] = fmaxf(acc[tl][g2], 0.f);
  store_tiles(Yb, lane, ct, marr, acc);
  conv_pass<4, 1, 256>(XE, wr + OFF1, down_b + r * 64, 0, lane, ct, marr, tarr, hreg);
  __syncthreads();   // Yb complete; all XE reads done
  conv_pass<2, 2, 128>(Yb, wr + OFF2, b2_0 + r * 64, 1, lane, ct, marr, tarr, acc);
#pragma unroll
  for (int tl = 0; tl < NT; ++tl)
#pragma unroll
    for (int g2 = 0; g2 < 4; ++g2)
      hreg[tl][g2] = fmaxf(fmaxf(acc[tl][g2], 0.f) + hreg[tl][g2], 0.f);
  store_tiles(Hb, lane, ct, marr, hreg);               // overwrites XE space
  if (tid < 16) *(uint64_t*)(Hb + 80 * 128 + tid * 8) = 0;  // H zero row
  __syncthreads();

  // ---- levels 1..7 (rolled loop; wave-uniform runtime d/ntap) ----
#pragma unroll 1
  for (int l = 1; l <= 7; ++l) {
    int d = 1 << l;
    bool two = (l <= 3);
    const short* wl = wr + OFFL0 + (l - 1) * 16384;
    const float* bb1 = b1s + (r * 7 + (l - 1)) * 64;
    const float* bb2 = b2s + (r * 7 + (l - 1)) * 64;
    conv_rt(Hb, wl, bb1, d, two, lane, ct, marr, tarr, acc);
#pragma unroll
    for (int tl = 0; tl < NT; ++tl)
#pragma unroll
      for (int g2 = 0; g2 < 4; ++g2) acc[tl][g2] = fmaxf(acc[tl][g2], 0.f);
    store_tiles(Yb, lane, ct, marr, acc);
    __syncthreads();
    conv_rt(Yb, wl + 8192, bb2, d, two, lane, ct, marr, tarr, acc);
#pragma unroll
    for (int tl = 0; tl < NT; ++tl)
#pragma unroll
      for (int g2 = 0; g2 < 4; ++g2)
        hreg[tl][g2] = fmaxf(fmaxf(acc[tl][g2], 0.f) + hreg[tl][g2], 0.f);
    store_tiles(Hb, lane, ct, marr, hreg);
    __syncthreads();
  }

  // ---- epilogue: masked last-step (t==9), reduce over 8 sequences ----
  float s0 = 0, s1 = 0, s2 = 0, s3 = 0;
#pragma unroll
  for (int tl = 0; tl < NT; ++tl) {
    float mk = (tarr[tl] == 9) ? mkv[marr[tl] / 10] : 0.f;
    s0 += hreg[tl][0] * mk;
    s1 += hreg[tl][1] * mk;
    s2 += hreg[tl][2] * mk;
    s3 += hreg[tl][3] * mk;
  }
#pragma unroll
  for (int mk2 = 1; mk2 <= 8; mk2 <<= 1) {
    s0 += __shfl_xor(s0, mk2);
    s1 += __shfl_xor(s1, mk2);
    s2 += __shfl_xor(s2, mk2);
    s3 += __shfl_xor(s3, mk2);
  }
  if ((lane & 15) == 0) {
    int base = ((r * Bb + b) * 8 + chunk) * 64 + ct * 16 + (lane >> 4) * 4;
    P[base + 0] = s0;
    P[base + 1] = s1;
    P[base + 2] = s2;
    P[base + 3] = s3;
  }
}

// ---------------------------------------------------------------------------
// out[b][i] = sum_r sum_c (sum_p P[r][b][p][c]) * rel_w[r][c][i]
// ---------------------------------------------------------------------------
extern "C" __global__ void reduce_kernel(const float* __restrict__ P,
                                         const float* __restrict__ rel_w,
                                         float* __restrict__ out) {
  __shared__ float Sl[Rr * Cc];
  int b = blockIdx.x, i = threadIdx.x;
  for (int idx = i; idx < Rr * Cc; idx += 64) {
    int rr = idx >> 6, cc = idx & 63;
    float s = 0.f;
    for (int p = 0; p < 8; ++p) s += P[((rr * Bb + b) * 8 + p) * 64 + cc];
    Sl[idx] = s;
  }
  __syncthreads();
  float acc = 0.f;
  for (int r = 0; r < Rr; ++r)
#pragma unroll
    for (int cc = 0; cc < 64; ++cc)
      acc += Sl[r * Cc + cc] * rel_w[(r * Cc + cc) * Ii + i];
  out[b * Ii + i] = acc;
}

// ---------------------------------------------------------------------------
extern "C" void kernel_launch(void* const* d_in, const int* in_sizes, int n_in,
                              void* d_out, int out_size, void* d_ws, size_t ws_size,
                              hipStream_t stream) {
  const float* emb    = (const float*)d_in[0];
  const float* w1_0   = (const float*)d_in[1];
  const float* b1_0   = (const float*)d_in[2];
  const float* w2_0   = (const float*)d_in[3];
  const float* b2_0   = (const float*)d_in[4];
  const float* down_w = (const float*)d_in[5];
  const float* down_b = (const float*)d_in[6];
  const float* w1s    = (const float*)d_in[7];
  const float* b1s    = (const float*)d_in[8];
  const float* w2s    = (const float*)d_in[9];
  const float* b2s    = (const float*)d_in[10];
  const float* rel_w  = (const float*)d_in[11];
  const int* align_   = (const int*)d_in[12];
  const int* nidx     = (const int*)d_in[13];
  const int* nmask    = (const int*)d_in[14];

  float* P  = (float*)d_ws;                       // 4*64*8*64 f32 = 512 KB
  short* Wf = (short*)((char*)d_ws + 524288);     // 589824 bf16 = 1.15 MB

  prep_kernel<<<768, 256, 0, stream>>>(w1_0, w2_0, down_w, w1s, w2s, Wf);
  tcn_mfma<<<2048, 256, 0, stream>>>(emb, align_, nidx, nmask, b1_0, b2_0, down_b,
                                     b1s, b2s, Wf, P);
  reduce_kernel<<<Bb, Cc, 0, stream>>>(P, rel_w, (float*)d_out);
}

// Round 6
// 61.430 us; speedup vs baseline: 1.2801x; 1.2369x over previous
//
#include <hip/hip_runtime.h>
#include <hip/hip_bf16.h>
#include <stdint.h>

constexpr int NUM_NODES = 120000;
constexpr int Tn = 10;
constexpr int Bb = 64, Rr = 4, Nn = 64, Cc = 64, Ii = 64;
constexpr int G = 8;            // sequences per block
constexpr int RSTR  = 147456;   // per-relation Wf stride (bf16 elems)
constexpr int OFF0  = 0;        // L0 w1   [tap2][ct4][ks4][lane64][8]
constexpr int OFF1  = 16384;    // L0 down [ct4][ks4][lane64][8]
constexpr int OFF2  = 24576;    // L0 w2   [tap2][ct4][ks2][lane64][8]
constexpr int OFFL0 = 32768;    // levels  14 x [tap2][ct4][ks2][lane64][8]

// LDS byte offsets (H-chain aliases the dead X region)
constexpr int OFF_X  = 0;       // 80 cols x 256B = 20480
constexpr int OFF_H0 = 0;       // 48 x 128 = 6144   (valid after level 0)
constexpr int OFF_H1 = 6144;    // 32 x 128 = 4096
constexpr int OFF_H2 = 10240;   // 16 x 128 = 2048
constexpr int OFF_H3 = 12288;   // 8 x 128 (+pad overlap, ordering-safe)
constexpr int OFF_Y  = 20480;   // 80 x 128 = 10240 (all Y levels share)
constexpr int ZOFF   = 30720;   // 256B zero row
constexpr int SMEMB  = 30976;

typedef __attribute__((ext_vector_type(8))) short bf16x8;
typedef __attribute__((ext_vector_type(4))) float f32x4;
typedef __attribute__((ext_vector_type(4))) short s16x4;

__device__ __forceinline__ short f2bf(float f) {
  __hip_bfloat16 h = __float2bfloat16(f);
  return *reinterpret_cast<short*>(&h);
}
__device__ __forceinline__ float bf2f(short s) {
  union { unsigned int u; float f; } x;
  x.u = ((unsigned int)(unsigned short)s) << 16;
  return x.f;
}

// ---------------------------------------------------------------------------
// Bake weights into per-lane MFMA A-fragments (bf16). (verified rounds 3-5)
// ---------------------------------------------------------------------------
extern "C" __global__ void prep_kernel(const float* __restrict__ w1_0,
                                       const float* __restrict__ w2_0,
                                       const float* __restrict__ down_w,
                                       const float* __restrict__ w1s,
                                       const float* __restrict__ w2s,
                                       short* __restrict__ Wf) {
  int i0 = blockIdx.x * blockDim.x + threadIdx.x;
  int stride = gridDim.x * blockDim.x;
  for (int e = i0; e < Rr * RSTR; e += stride) {
    int r = e / RSTR, q = e - r * RSTR;
    float v;
    if (q < 16384) {
      int j = q & 7, lane = (q >> 3) & 63, ks = (q >> 9) & 3, ct = (q >> 11) & 3, tap = (q >> 13) & 1;
      int cout = ct * 16 + (lane & 15), cin = ks * 32 + (lane >> 4) * 8 + j;
      v = w1_0[((r * 64 + cout) * 128 + cin) * 2 + tap];
    } else if (q < 24576) {
      int q2 = q - 16384;
      int j = q2 & 7, lane = (q2 >> 3) & 63, ks = (q2 >> 9) & 3, ct = (q2 >> 11) & 3;
      int cout = ct * 16 + (lane & 15), cin = ks * 32 + (lane >> 4) * 8 + j;
      v = down_w[(r * 64 + cout) * 128 + cin];
    } else if (q < 32768) {
      int q2 = q - 24576;
      int j = q2 & 7, lane = (q2 >> 3) & 63, ks = (q2 >> 9) & 1, ct = (q2 >> 10) & 3, tap = (q2 >> 12) & 1;
      int cout = ct * 16 + (lane & 15), cin = ks * 32 + (lane >> 4) * 8 + j;
      v = w2_0[((r * 64 + cout) * 64 + cin) * 2 + tap];
    } else {
      int q2 = q - 32768;
      int lc = q2 >> 13;
      int l = lc >> 1, jw = lc & 1;
      int q3 = q2 & 8191;
      int j = q3 & 7, lane = (q3 >> 3) & 63, ks = (q3 >> 9) & 1, ct = (q3 >> 10) & 3, tap = (q3 >> 12) & 1;
      int cout = ct * 16 + (lane & 15), cin = ks * 32 + (lane >> 4) * 8 + j;
      const float* src = jw ? w2s : w1s;
      v = src[(((r * 7 + l) * 64 + cout) * 64 + cin) * 2 + tap];
    }
    Wf[e] = f2bf(v);
  }
}

// ---------------------------------------------------------------------------
// Sparse-slot conv pass. Input cols packed slot-major (col = slot*8+seq).
// T1/T0: per-output-slot input-slot maps (-1 => zero row). All static.
// ---------------------------------------------------------------------------
template <int KSN, int NMT, int NTAP, int ROWB>
__device__ __forceinline__ void conv_sp(const char* __restrict__ sm, int srcOff,
                                        const short* __restrict__ wf1,
                                        const short* __restrict__ wf0,
                                        const float* __restrict__ bias,
                                        const int (&T1)[NMT * 2], const int (&T0)[NMT * 2],
                                        int lane, int ct, f32x4 (&acc)[NMT]) {
  const int c16 = (lane >> 4) * 16;
  const int seq = lane & 7;
  const int hi = (lane & 15) >> 3;
  const int sw = seq << 4;
  float bv[4];
#pragma unroll
  for (int g = 0; g < 4; ++g) bv[g] = bias[ct * 16 + (lane >> 4) * 4 + g];
#pragma unroll
  for (int mt = 0; mt < NMT; ++mt) acc[mt] = (f32x4){bv[0], bv[1], bv[2], bv[3]};
  bf16x8 af1[KSN], af0[KSN];
#pragma unroll
  for (int ks = 0; ks < KSN; ++ks)
    af1[ks] = *(const bf16x8*)(wf1 + ((ct * KSN + ks) * 64 + lane) * 8);
  if (NTAP == 2) {
#pragma unroll
    for (int ks = 0; ks < KSN; ++ks)
      af0[ks] = *(const bf16x8*)(wf0 + ((ct * KSN + ks) * 64 + lane) * 8);
  }
#pragma unroll
  for (int mt = 0; mt < NMT; ++mt) {
    int s1 = hi ? T1[2 * mt + 1] : T1[2 * mt];
    const char* p1 = sm + ((s1 < 0) ? ZOFF : srcOff + (s1 * 8 + seq) * ROWB);
#pragma unroll
    for (int ks = 0; ks < KSN; ++ks) {
      bf16x8 b = *(const bf16x8*)(p1 + ((ks * 64 + c16) ^ sw));
      acc[mt] = __builtin_amdgcn_mfma_f32_16x16x32_bf16(af1[ks], b, acc[mt], 0, 0, 0);
    }
    if (NTAP == 2) {
      int s0 = hi ? T0[2 * mt + 1] : T0[2 * mt];
      const char* p0 = sm + ((s0 < 0) ? ZOFF : srcOff + (s0 * 8 + seq) * ROWB);
#pragma unroll
      for (int ks = 0; ks < KSN; ++ks) {
        bf16x8 b = *(const bf16x8*)(p0 + ((ks * 64 + c16) ^ sw));
        acc[mt] = __builtin_amdgcn_mfma_f32_16x16x32_bf16(af0[ks], b, acc[mt], 0, 0, 0);
      }
    }
  }
}

template <int NMT>
__device__ __forceinline__ void store_sp(char* __restrict__ sm, int dstOff, int lane,
                                         int ct, const f32x4 (&v)[NMT]) {
  const int co = ct * 32 + (lane >> 4) * 8;
#pragma unroll
  for (int mt = 0; mt < NMT; ++mt) {
    int oc = 16 * mt + (lane & 15);
    s16x4 p;
#pragma unroll
    for (int g = 0; g < 4; ++g) p[g] = f2bf(v[mt][g]);
    *(s16x4*)(sm + dstOff + oc * 128 + (co ^ ((oc & 7) << 4))) = p;
  }
}

#define RELU_ALL(A, N)                                        \
  _Pragma("unroll") for (int _t = 0; _t < N; ++_t)            \
      _Pragma("unroll") for (int _g = 0; _g < 4; ++_g)        \
          A[_t][_g] = fmaxf(A[_t][_g], 0.f);

// residual: h = relu(relu(acc) + H_prev(bf16 from LDS))
template <int NMT>
__device__ __forceinline__ void resid_sp(const char* __restrict__ sm, int prevOff,
                                         const int (&R)[NMT * 2], int lane, int ct,
                                         f32x4 (&a)[NMT]) {
  const int co = ct * 32 + (lane >> 4) * 8;
  const int seq = lane & 7;
  const int hi = (lane & 15) >> 3;
  const int sw = seq << 4;
#pragma unroll
  for (int mt = 0; mt < NMT; ++mt) {
    int rs = hi ? R[2 * mt + 1] : R[2 * mt];
    const char* p = sm + ((rs < 0) ? ZOFF : prevOff + (rs * 8 + seq) * 128);
    s16x4 q = *(const s16x4*)(p + (co ^ sw));
#pragma unroll
    for (int g = 0; g < 4; ++g)
      a[mt][g] = fmaxf(fmaxf(a[mt][g], 0.f) + bf2f(q[g]), 0.f);
  }
}

// ---------------------------------------------------------------------------
// Main: gather + temporally-sparse TCN (44 cols/seq instead of 150).
// Block = 256 thr = 4 waves (wave = cout-tile of 16), 8 valid sequences.
// ---------------------------------------------------------------------------
extern "C" __global__ void __launch_bounds__(256, 4)
tcn_mfma(const float* __restrict__ emb, const int* __restrict__ align_,
         const int* __restrict__ nidx, const int* __restrict__ nmask,
         const float* __restrict__ b1_0, const float* __restrict__ b2_0,
         const float* __restrict__ down_b, const float* __restrict__ b1s,
         const float* __restrict__ b2s, const short* __restrict__ Wf,
         float* __restrict__ P) {
  __shared__ char sm[SMEMB];
  __shared__ int rowid[80];
  __shared__ float mkv[G];
  __shared__ int mapg[G];
  __shared__ int totv;

  const int tid = threadIdx.x;
  const int lane = tid & 63, ct = tid >> 6;
  const int blk = blockIdx.x;
  const int r = blk >> 9;
  const int blkr = blk & 511;
  const int b = blkr >> 3, chunk = blkr & 7;

  // ---- ballot compaction of this (b,r)'s valid neighbors ----
  if (tid < 64) {
    int n = tid;
    int msk = nmask[(b * Rr + r) * Nn + n];
    unsigned long long bal = __ballot(msk != 0);
    if (tid < G) mapg[tid] = -1;
    if (tid == 0) totv = (int)__popcll(bal);
    int rank = (int)__popcll(bal & ((1ull << n) - 1ull));
    if (msk != 0 && rank >= chunk * G && rank < chunk * G + G)
      mapg[rank - chunk * G] = n;
  }
  if (tid >= 192 && tid < 224) *(uint64_t*)(sm + ZOFF + (tid - 192) * 8) = 0;
  __syncthreads();
  if (chunk * G >= totv) {           // inactive block: zero partial, exit
    if (tid < 64) P[((r * Bb + b) * 8 + chunk) * 64 + tid] = 0.f;
    return;
  }

  // col = t*8 + seq  (slot-major packing)
  if (tid < 80) {
    int t = tid >> 3, seq = tid & 7;
    int n2 = mapg[seq];
    int s = -1;
    if (n2 >= 0) {
      int ent = nidx[(b * Rr + r) * Nn + n2];
      s = align_[ent * Tn + t];
    }
    rowid[tid] = (n2 >= 0 && s >= 0) ? s : -1;
    if (t == 0) mkv[seq] = (n2 >= 0) ? 1.0f : 0.0f;
  }
  __syncthreads();

  // gather: 80 cols x 128 d, f32 -> bf16, swizzled LDS write
#pragma unroll
  for (int it = 0; it < 10; ++it) {
    int idx = tid + it * 256;
    int col = idx >> 5, d4 = idx & 31;
    int row = rowid[col];
    int t = col >> 3;
    s16x4 p = {0, 0, 0, 0};
    if (row >= 0) {
      const float4 v = *(const float4*)(emb + ((size_t)t * NUM_NODES + row) * 128 + d4 * 4);
      p[0] = f2bf(v.x); p[1] = f2bf(v.y); p[2] = f2bf(v.z); p[3] = f2bf(v.w);
    }
    *(s16x4*)(sm + OFF_X + col * 256 + ((d4 * 8) ^ ((col & 7) << 4))) = p;
  }
  __syncthreads();

  const short* wr = Wf + r * RSTR;

  // ---- pass1: Y0 = relu(conv1_0(X)), all t ----
  {
    constexpr int T1[10] = {0, 1, 2, 3, 4, 5, 6, 7, 8, 9};
    constexpr int T0[10] = {-1, 0, 1, 2, 3, 4, 5, 6, 7, 8};
    f32x4 a[5];
    conv_sp<4, 5, 2, 256>(sm, OFF_X, wr + OFF0 + 8192, wr + OFF0, b1_0 + r * 64,
                          T1, T0, lane, ct, a);
    RELU_ALL(a, 5)
    store_sp<5>(sm, OFF_Y, lane, ct, a);
  }
  // ---- pass2: down(X) at odd t, carried in regs ----
  f32x4 accD[3];
  {
    constexpr int TD[6] = {1, 3, 5, 7, 9, 9};
    conv_sp<4, 3, 1, 256>(sm, OFF_X, wr + OFF1, wr + OFF1, down_b + r * 64,
                          TD, TD, lane, ct, accD);
  }
  __syncthreads();
  // ---- pass3: H0 = relu(relu(conv2_0(Y0)) + down) at odd t ----
  {
    constexpr int T1[6] = {1, 3, 5, 7, 9, 9};
    constexpr int T0[6] = {0, 2, 4, 6, 8, 8};
    f32x4 a[3];
    conv_sp<2, 3, 2, 128>(sm, OFF_Y, wr + OFF2 + 4096, wr + OFF2, b2_0 + r * 64,
                          T1, T0, lane, ct, a);
#pragma unroll
    for (int mt = 0; mt < 3; ++mt)
#pragma unroll
      for (int g = 0; g < 4; ++g)
        a[mt][g] = fmaxf(fmaxf(a[mt][g], 0.f) + accD[mt][g], 0.f);
    store_sp<3>(sm, OFF_H0, lane, ct, a);
  }
  __syncthreads();
  // ---- level 1 (d=2): Y1 at H0-slots; H1 at [1,5,9] ----
  {
    constexpr int T1[6] = {0, 1, 2, 3, 4, 4};
    constexpr int T0[6] = {-1, 0, 1, 2, 3, 3};
    f32x4 a[3];
    const short* wb = wr + OFFL0;
    conv_sp<2, 3, 2, 128>(sm, OFF_H0, wb + 4096, wb, b1s + (r * 7 + 0) * 64,
                          T1, T0, lane, ct, a);
    RELU_ALL(a, 3)
    store_sp<3>(sm, OFF_Y, lane, ct, a);
  }
  __syncthreads();
  {
    constexpr int T1[4] = {0, 2, 4, 4};
    constexpr int T0[4] = {-1, 1, 3, 3};
    constexpr int R[4] = {0, 2, 4, 4};
    f32x4 a[2];
    const short* wb = wr + OFFL0 + 8192;
    conv_sp<2, 2, 2, 128>(sm, OFF_Y, wb + 4096, wb, b2s + (r * 7 + 0) * 64,
                          T1, T0, lane, ct, a);
    resid_sp<2>(sm, OFF_H0, R, lane, ct, a);
    store_sp<2>(sm, OFF_H1, lane, ct, a);
  }
  __syncthreads();
  // ---- level 2 (d=4): Y2 at [1,5,9]; H2 at [1,9] ----
  {
    constexpr int T1[4] = {0, 1, 2, 2};
    constexpr int T0[4] = {-1, 0, 1, 1};
    f32x4 a[2];
    const short* wb = wr + OFFL0 + 16384;
    conv_sp<2, 2, 2, 128>(sm, OFF_H1, wb + 4096, wb, b1s + (r * 7 + 1) * 64,
                          T1, T0, lane, ct, a);
    RELU_ALL(a, 2)
    store_sp<2>(sm, OFF_Y, lane, ct, a);
  }
  __syncthreads();
  {
    constexpr int T1[2] = {0, 2};
    constexpr int T0[2] = {-1, 1};
    constexpr int R[2] = {0, 2};
    f32x4 a[1];
    const short* wb = wr + OFFL0 + 16384 + 8192;
    conv_sp<2, 1, 2, 128>(sm, OFF_Y, wb + 4096, wb, b2s + (r * 7 + 1) * 64,
                          T1, T0, lane, ct, a);
    resid_sp<1>(sm, OFF_H1, R, lane, ct, a);
    store_sp<1>(sm, OFF_H2, lane, ct, a);
  }
  __syncthreads();
  // ---- level 3 (d=8): Y3 at [1,9]; H3 at [9] ----
  {
    constexpr int T1[2] = {0, 1};
    constexpr int T0[2] = {-1, 0};
    f32x4 a[1];
    const short* wb = wr + OFFL0 + 32768;
    conv_sp<2, 1, 2, 128>(sm, OFF_H2, wb + 4096, wb, b1s + (r * 7 + 2) * 64,
                          T1, T0, lane, ct, a);
    RELU_ALL(a, 1)
    store_sp<1>(sm, OFF_Y, lane, ct, a);
  }
  __syncthreads();
  {
    constexpr int T1[2] = {1, 1};
    constexpr int T0[2] = {0, 0};
    constexpr int R[2] = {1, 1};
    f32x4 a[1];
    const short* wb = wr + OFFL0 + 32768 + 8192;
    conv_sp<2, 1, 2, 128>(sm, OFF_Y, wb + 4096, wb, b2s + (r * 7 + 2) * 64,
                          T1, T0, lane, ct, a);
    resid_sp<1>(sm, OFF_H2, R, lane, ct, a);
    store_sp<1>(sm, OFF_H3, lane, ct, a);
  }
  __syncthreads();

  // ---- levels 4..7 (d>=16, single tap, single slot t=9) ----
  f32x4 hfin[1];
#pragma unroll 1
  for (int li = 0; li < 4; ++li) {
    const short* base = wr + OFFL0 + (3 + li) * 16384;
    const int prevOff = OFF_H3 + li * 1024;
    constexpr int TA[2] = {0, 0};
    {
      f32x4 a[1];
      conv_sp<2, 1, 1, 128>(sm, prevOff, base + 4096, base + 4096,
                            b1s + (r * 7 + 3 + li) * 64, TA, TA, lane, ct, a);
      RELU_ALL(a, 1)
      store_sp<1>(sm, OFF_Y, lane, ct, a);
    }
    __syncthreads();
    {
      f32x4 a[1];
      conv_sp<2, 1, 1, 128>(sm, OFF_Y, base + 8192 + 4096, base + 8192 + 4096,
                            b2s + (r * 7 + 3 + li) * 64, TA, TA, lane, ct, a);
      resid_sp<1>(sm, prevOff, TA, lane, ct, a);
      store_sp<1>(sm, prevOff + 1024, lane, ct, a);
      hfin[0] = a[0];
    }
    __syncthreads();
  }

  // ---- epilogue: mask + reduce over 8 sequences (lanes 0-7 of each group) ----
  float mk = ((lane & 15) < 8) ? mkv[lane & 7] : 0.f;
  float s0 = hfin[0][0] * mk, s1 = hfin[0][1] * mk, s2 = hfin[0][2] * mk, s3 = hfin[0][3] * mk;
#pragma unroll
  for (int m2 = 1; m2 <= 4; m2 <<= 1) {
    s0 += __shfl_xor(s0, m2);
    s1 += __shfl_xor(s1, m2);
    s2 += __shfl_xor(s2, m2);
    s3 += __shfl_xor(s3, m2);
  }
  if ((lane & 15) == 0) {
    int base = ((r * Bb + b) * 8 + chunk) * 64 + ct * 16 + (lane >> 4) * 4;
    P[base + 0] = s0;
    P[base + 1] = s1;
    P[base + 2] = s2;
    P[base + 3] = s3;
  }
}

// ---------------------------------------------------------------------------
// out[b][i] = sum_r sum_c (sum_p P[r][b][p][c]) * rel_w[r][c][i]
// ---------------------------------------------------------------------------
extern "C" __global__ void reduce_kernel(const float* __restrict__ P,
                                         const float* __restrict__ rel_w,
                                         float* __restrict__ out) {
  __shared__ float Sl[Rr * Cc];
  int b = blockIdx.x, i = threadIdx.x;
  for (int idx = i; idx < Rr * Cc; idx += 64) {
    int rr = idx >> 6, cc = idx & 63;
    float s = 0.f;
    for (int p = 0; p < 8; ++p) s += P[((rr * Bb + b) * 8 + p) * 64 + cc];
    Sl[idx] = s;
  }
  __syncthreads();
  float acc = 0.f;
  for (int r = 0; r < Rr; ++r)
#pragma unroll
    for (int cc = 0; cc < 64; ++cc)
      acc += Sl[r * Cc + cc] * rel_w[(r * Cc + cc) * Ii + i];
  out[b * Ii + i] = acc;
}

// ---------------------------------------------------------------------------
extern "C" void kernel_launch(void* const* d_in, const int* in_sizes, int n_in,
                              void* d_out, int out_size, void* d_ws, size_t ws_size,
                              hipStream_t stream) {
  const float* emb    = (const float*)d_in[0];
  const float* w1_0   = (const float*)d_in[1];
  const float* b1_0   = (const float*)d_in[2];
  const float* w2_0   = (const float*)d_in[3];
  const float* b2_0   = (const float*)d_in[4];
  const float* down_w = (const float*)d_in[5];
  const float* down_b = (const float*)d_in[6];
  const float* w1s    = (const float*)d_in[7];
  const float* b1s    = (const float*)d_in[8];
  const float* w2s    = (const float*)d_in[9];
  const float* b2s    = (const float*)d_in[10];
  const float* rel_w  = (const float*)d_in[11];
  const int* align_   = (const int*)d_in[12];
  const int* nidx     = (const int*)d_in[13];
  const int* nmask    = (const int*)d_in[14];

  float* P  = (float*)d_ws;                       // 4*64*8*64 f32 = 512 KB
  short* Wf = (short*)((char*)d_ws + 524288);     // 589824 bf16 = 1.15 MB

  prep_kernel<<<768, 256, 0, stream>>>(w1_0, w2_0, down_w, w1s, w2s, Wf);
  tcn_mfma<<<2048, 256, 0, stream>>>(emb, align_, nidx, nmask, b1_0, b2_0, down_b,
                                     b1s, b2s, Wf, P);
  reduce_kernel<<<Bb, Cc, 0, stream>>>(P, rel_w, (float*)d_out);
}